// Round 1
// baseline (522.314 us; speedup 1.0000x reference)
//
#include <hip/hip_runtime.h>
#include <hip/hip_bf16.h>

namespace {

constexpr int B = 64, G = 512, D = 128, H = 8, KD = 16, NS = 20;
constexpr float NORM = 0.25f; // 1/sqrt(KD)

// One block (512 threads) per (b, h). Phase 1: project Q for this segment into
// LDS. Phase 2: loop over 64-key tiles: stage h rows -> LDS, project K/V tile
// -> LDS, online-softmax attention. TPQ threads cooperate per query
// (TPQ=1 for the big custom segment; 16/64 for station/depot).
template<int SEG, int TPQ>
__global__ __launch_bounds__(512)
void attn_seg_kernel(const float* __restrict__ q, const float* __restrict__ hb,
                     const float* __restrict__ Wq, const float* __restrict__ Wk,
                     const float* __restrict__ Wv, float* __restrict__ heads)
{
  constexpr int Lq   = (SEG == 0) ? 1 : (SEG == 1) ? NS : (G - 1 - NS); // 1,20,491
  constexpr int QOFF = (SEG == 0) ? 0 : (SEG == 1) ? 1  : (1 + NS);
  constexpr int Ln   = (SEG == 0) ? (G - 1 - NS) : (SEG == 1) ? (G - NS) : G; // 491,492,512
  constexpr int NCQ  = (Lq + 31) / 32;   // 32-row Q chunks
  constexpr int NT   = (Ln + 63) / 64;   // 64-key tiles

  const int hh  = blockIdx.x;
  const int b   = blockIdx.y;
  const int tid = threadIdx.x;

  __shared__ float smem[15360]; // 60 KB, phase-overlapped regions
  // phase 1 layout
  float* const Qlds   = smem;          // 512*17  = 8704  (pad 17 kills conflicts)
  float* const qchunk = smem + 8704;   // 32*132  = 4224  (pad 132: 4-float aligned)
  float* const Wqlds  = smem + 12928;  // 2048
  // phase 2 layout (reuses phase-1 space)
  float* const Wklds  = smem;          // 2048
  float* const Wvlds  = smem + 2048;   // 2048
  float* const chunk  = smem + 4096;   // 64*132 = 8448
  float* const Kt     = smem + 12544;  // 64*16  = 1024
  float* const Vt     = smem + 13568;  // 64*16  = 1024

  // ---------------- phase 1: Q projection (norm folded in) ----------------
  ((float4*)Wqlds)[tid] = ((const float4*)(Wq + (size_t)hh * D * KD))[tid];
  __syncthreads();
  for (int c = 0; c < NCQ; ++c) {
    #pragma unroll
    for (int i = 0; i < 2; ++i) {            // stage 32 q rows (1024 float4)
      int idx = tid + i * 512;
      int row = idx >> 5, col = idx & 31;
      int grow = c * 32 + row;
      int gq = QOFF + (grow < Lq ? grow : Lq - 1); // clamp: content unused
      ((float4*)qchunk)[row * 33 + col] =
          ((const float4*)(q + ((size_t)b * G + gq) * D))[col];
    }
    __syncthreads();
    {
      int k = tid & 15, r = tid >> 4;        // 32 rows x 16 k = 512 tasks
      const float* crow = qchunk + r * 132;
      float acc = 0.f;
      #pragma unroll 8
      for (int d = 0; d < D; ++d) acc += crow[d] * Wqlds[d * 16 + k];
      Qlds[(c * 32 + r) * 17 + k] = acc * NORM;
    }
    __syncthreads();
  }

  const int qidx = tid / TPQ;
  const int lane = tid % TPQ;
  float Qr[16];
  {
    const int qi = (qidx < Lq) ? qidx : 0;
    #pragma unroll
    for (int j = 0; j < 16; ++j) Qr[j] = Qlds[qi * 17 + j];
  }
  __syncthreads(); // Qlds dead; space reused below

  // ---------------- phase 2: K/V tiles + online softmax ----------------
  ((float4*)Wklds)[tid] = ((const float4*)(Wk + (size_t)hh * D * KD))[tid];
  ((float4*)Wvlds)[tid] = ((const float4*)(Wv + (size_t)hh * D * KD))[tid];

  float m = -1e30f, l = 0.f;
  float acc[16];
  #pragma unroll
  for (int j = 0; j < 16; ++j) acc[j] = 0.f;

  for (int t = 0; t < NT; ++t) {
    const int base = t * 64;
    const int tlen = (Ln - base < 64) ? (Ln - base) : 64;
    #pragma unroll
    for (int i = 0; i < 4; ++i) {            // stage 64 h rows (2048 float4)
      int idx = tid + i * 512;
      int row = idx >> 5, col = idx & 31;
      int n = base + row; if (n >= Ln) n = Ln - 1;
      int hr;
      if (SEG == 0)      hr = n + 1 + NS;             // h_custom: rows 21..511
      else if (SEG == 1) hr = (n == 0) ? 0 : n + NS;  // h_other: {0} U 21..511
      else               hr = n;                      // all rows
      ((float4*)chunk)[row * 33 + col] =
          ((const float4*)(hb + ((size_t)b * G + hr) * D))[col];
    }
    __syncthreads();
    #pragma unroll
    for (int p = 0; p < 2; ++p) {            // project K/V tile: 64x16 each
      int k = tid & 15, r = (tid >> 4) + p * 32;
      const float* crow = chunk + r * 132;
      float aK = 0.f, aV = 0.f;
      #pragma unroll 8
      for (int d = 0; d < D; ++d) {
        float cv = crow[d];
        aK += cv * Wklds[d * 16 + k];
        aV += cv * Wvlds[d * 16 + k];
      }
      Kt[r * 16 + k] = aK;
      Vt[r * 16 + k] = aV;
    }
    __syncthreads();
    for (int j = lane; j < tlen; j += TPQ) { // broadcast LDS reads (same addr)
      const float4* kr = (const float4*)(Kt + j * 16);
      float4 k0 = kr[0], k1 = kr[1], k2 = kr[2], k3 = kr[3];
      float s = Qr[0]*k0.x + Qr[1]*k0.y + Qr[2]*k0.z + Qr[3]*k0.w
              + Qr[4]*k1.x + Qr[5]*k1.y + Qr[6]*k1.z + Qr[7]*k1.w
              + Qr[8]*k2.x + Qr[9]*k2.y + Qr[10]*k2.z + Qr[11]*k2.w
              + Qr[12]*k3.x + Qr[13]*k3.y + Qr[14]*k3.z + Qr[15]*k3.w;
      if (s > m) {                           // rare rescale branch
        const float sc = __expf(m - s);
        l *= sc;
        #pragma unroll
        for (int jj = 0; jj < 16; ++jj) acc[jj] *= sc;
        m = s;
      }
      const float pp = __expf(s - m);
      l += pp;
      const float4* vr = (const float4*)(Vt + j * 16);
      float4 v0 = vr[0], v1 = vr[1], v2 = vr[2], v3 = vr[3];
      acc[0]  += pp*v0.x; acc[1]  += pp*v0.y; acc[2]  += pp*v0.z; acc[3]  += pp*v0.w;
      acc[4]  += pp*v1.x; acc[5]  += pp*v1.y; acc[6]  += pp*v1.z; acc[7]  += pp*v1.w;
      acc[8]  += pp*v2.x; acc[9]  += pp*v2.y; acc[10] += pp*v2.z; acc[11] += pp*v2.w;
      acc[12] += pp*v3.x; acc[13] += pp*v3.y; acc[14] += pp*v3.z; acc[15] += pp*v3.w;
    }
    __syncthreads();
  }

  if constexpr (TPQ > 1) {                   // merge online-softmax state
    #pragma unroll
    for (int off = TPQ >> 1; off > 0; off >>= 1) {
      float m2 = __shfl_xor(m, off);
      float l2 = __shfl_xor(l, off);
      float mn = fmaxf(m, m2);
      float s1 = __expf(m - mn), s2 = __expf(m2 - mn);
      l = l * s1 + l2 * s2;
      #pragma unroll
      for (int jj = 0; jj < 16; ++jj)
        acc[jj] = acc[jj] * s1 + __shfl_xor(acc[jj], off) * s2;
      m = mn;
    }
  }

  if (lane == 0 && qidx < Lq) {
    const float inv = 1.0f / l;
    float4* dst = (float4*)(heads + (((size_t)b * G + QOFF + qidx) * H + hh) * KD);
    dst[0] = make_float4(acc[0]*inv,  acc[1]*inv,  acc[2]*inv,  acc[3]*inv);
    dst[1] = make_float4(acc[4]*inv,  acc[5]*inv,  acc[6]*inv,  acc[7]*inv);
    dst[2] = make_float4(acc[8]*inv,  acc[9]*inv,  acc[10]*inv, acc[11]*inv);
    dst[3] = make_float4(acc[12]*inv, acc[13]*inv, acc[14]*inv, acc[15]*inv);
  }
}

// In-place output projection: row (b,g) of `data` holds heads[h*16+k] (128
// values); out[b,g,e] = sum_hk heads[hk] * Wout[hk][e]. Rows are independent:
// stage 64 rows -> LDS -> sync -> overwrite. W_out (H,KD,E) is already the
// flat [hk][e] matrix.
__global__ __launch_bounds__(256)
void out_proj_kernel(float* __restrict__ data, const float* __restrict__ Wout)
{
  __shared__ float Alds[64 * 128]; // 32 KB
  const int tid = threadIdx.x;
  const size_t rowbase = (size_t)blockIdx.x * 64;
  #pragma unroll
  for (int i = 0; i < 8; ++i) {
    int idx = tid + i * 256;
    ((float4*)Alds)[idx] = ((const float4*)(data + rowbase * 128))[idx];
  }
  __syncthreads();
  const int eq = tid & 31;  // float4 column
  const int r0 = tid >> 5;  // 0..7; rows r0, r0+8, ..., r0+56
  float4 accv[8];
  #pragma unroll
  for (int i = 0; i < 8; ++i) accv[i] = make_float4(0.f, 0.f, 0.f, 0.f);
  for (int d = 0; d < 128; ++d) {
    float4 w = ((const float4*)(Wout + (size_t)d * 128))[eq]; // L2-hot 64 KB
    #pragma unroll
    for (int i = 0; i < 8; ++i) {
      float a = Alds[(r0 + i * 8) * 128 + d]; // 2 addrs/wave -> broadcast
      accv[i].x += a * w.x; accv[i].y += a * w.y;
      accv[i].z += a * w.z; accv[i].w += a * w.w;
    }
  }
  #pragma unroll
  for (int i = 0; i < 8; ++i)
    ((float4*)(data + (rowbase + r0 + i * 8) * 128))[eq] = accv[i];
}

} // namespace

extern "C" void kernel_launch(void* const* d_in, const int* in_sizes, int n_in,
                              void* d_out, int out_size, void* d_ws, size_t ws_size,
                              hipStream_t stream) {
  const float* q    = (const float*)d_in[0];
  const float* h    = (const float*)d_in[1];
  const float* Wqd  = (const float*)d_in[2];
  const float* Wkc  = (const float*)d_in[3];
  const float* Wvc  = (const float*)d_in[4];
  const float* Wqs  = (const float*)d_in[5];
  const float* Wko  = (const float*)d_in[6];
  const float* Wvo  = (const float*)d_in[7];
  const float* Wqc  = (const float*)d_in[8];
  const float* Wka  = (const float*)d_in[9];
  const float* Wva  = (const float*)d_in[10];
  const float* Wout = (const float*)d_in[11];
  float* out = (float*)d_out; // heads buffer, then transformed in place

  dim3 grid(H, B);
  attn_seg_kernel<0, 64><<<grid, 512, 0, stream>>>(q, h, Wqd, Wkc, Wvc, out);
  attn_seg_kernel<1, 16><<<grid, 512, 0, stream>>>(q, h, Wqs, Wko, Wvo, out);
  attn_seg_kernel<2, 1 ><<<grid, 512, 0, stream>>>(q, h, Wqc, Wka, Wva, out);
  out_proj_kernel<<<G * B / 64, 256, 0, stream>>>(out, Wout);
}

// Round 2
// 106.034 us; speedup vs baseline: 4.9259x; 4.9259x over previous
//
#include <hip/hip_runtime.h>
#include <hip/hip_bf16.h>

namespace {

typedef _Float16 v4h __attribute__((ext_vector_type(4)));
typedef float    v4f __attribute__((ext_vector_type(4)));

constexpr int B = 64, G = 512, D = 128, H = 8, KD = 16, NS = 20;
constexpr float NORM = 0.25f;      // 1/sqrt(KD), folded into Wq fragments
constexpr int KP = 20;             // Kl row pad (f16) -> 40 B rows, <=2-way banks
constexpr int VP = 524;            // Vt row pad (f16) -> 1048 B rows, <=2-way banks
constexpr int QP = 20;             // Ql row pad
constexpr int QCH = 256;           // queries per LDS-resident chunk

__device__ __forceinline__ v4f mfma16(v4h a, v4h b, v4f c) {
  // D = A(16xK16) * B(K16x16) + C.  A: lane holds A[l&15][4*(l>>4)+i];
  // B: lane holds B[4*(l>>4)+i][l&15]; D: row=4*(l>>4)+i, col=l&15.
  return __builtin_amdgcn_mfma_f32_16x16x16f16(a, b, c, 0, 0, 0);
}

// One block (512 thr = 8 waves) per (b, head). blockIdx = hh*64 + b so the 8
// head-blocks of one batch share an XCD (round-robin %8 = b%8) -> h[b] L2-hot.
template<int SEG>
__global__ __launch_bounds__(512, 4)
void attn_seg_kernel(const float* __restrict__ q, const float* __restrict__ hb,
                     const float* __restrict__ Wq, const float* __restrict__ Wk,
                     const float* __restrict__ Wv, float* __restrict__ heads)
{
  constexpr int Lq   = SEG == 0 ? 1 : SEG == 1 ? NS : G - 1 - NS;  // 1,20,491
  constexpr int QOFF = SEG == 0 ? 0 : SEG == 1 ? 1  : 1 + NS;
  constexpr int Ln   = SEG == 0 ? G - 1 - NS : SEG == 1 ? G - NS : G; // 491,492,512
  constexpr int NCH  = (Ln + 31) / 64 * 2 + ((Ln & 63) && !(Ln & 32) ? 1 : 0); // see below
  constexpr int NCH2 = (Ln + 31) / 32;   // 32-key chunks (use this)
  constexpr int NST  = (Ln + 63) / 64;   // 64-row staging chunks
  constexpr int NQC  = (Lq + QCH - 1) / QCH;
  (void)NCH;

  __shared__ alignas(16) struct {
    char      ht[16384];            // 64 x 128 f16, 256 B rows, XOR-swizzled
    _Float16  Kl[512 * KP];         // K  [n][kd]
    _Float16  Vt[16 * VP];          // V^T[kd][n]
    _Float16  Ql[QCH * QP];         // Q  [q][kd] (norm folded)
  } sm;                             // 63,872 B

  const int hh   = blockIdx.x >> 6;
  const int b    = blockIdx.x & 63;
  const int tid  = threadIdx.x;
  const int w    = tid >> 6;
  const int lane = tid & 63;
  const int g    = lane >> 4, c = lane & 15;

  // ---- W fragments in registers (B-operand layout) ----
  v4h wA[8];                        // waves 0-3: Wk, waves 4-7: Wv
  v4h wQ[8];                        // waves 0-3 only
  {
    const float* Wt = (w < 4) ? Wk : Wv;
    #pragma unroll
    for (int dc = 0; dc < 8; ++dc)
      #pragma unroll
      for (int bb = 0; bb < 4; ++bb)
        wA[dc][bb] = (_Float16)Wt[((size_t)hh * D + dc * 16 + 4 * g + bb) * KD + c];
    if (w < 4) {
      #pragma unroll
      for (int dc = 0; dc < 8; ++dc)
        #pragma unroll
        for (int bb = 0; bb < 4; ++bb)
          wQ[dc][bb] = (_Float16)(Wq[((size_t)hh * D + dc * 16 + 4 * g + bb) * KD + c] * NORM);
    }
  }

  // ---- Phase B: K/V projection (K/V LDS-resident for whole block) ----
  const int sb = w & 3;
  for (int t = 0; t < NST; ++t) {
    const int base = t * 64;
    #pragma unroll
    for (int i = 0; i < 4; ++i) {    // stage 64 h rows -> f16 swizzled
      int idx = tid + i * 512, r = idx >> 5, jj = idx & 31;
      int n = base + r;
      int nn = n < Ln ? n : Ln - 1;
      int hr;
      if (SEG == 0)      hr = nn + 1 + NS;
      else if (SEG == 1) hr = (nn == 0) ? 0 : nn + NS;
      else               hr = nn;
      float4 v = ((const float4*)(hb + ((size_t)b * G + hr) * D))[jj];
      v4h hv = {(_Float16)v.x, (_Float16)v.y, (_Float16)v.z, (_Float16)v.w};
      *(v4h*)(sm.ht + r * 256 + ((8 * jj) ^ ((r & 7) << 4))) = hv;
    }
    __syncthreads();
    v4f acc = {0.f, 0.f, 0.f, 0.f};
    #pragma unroll
    for (int dc = 0; dc < 8; ++dc) {
      const v4h a = *(const v4h*)(sm.ht + (sb * 16 + c) * 256 +
                                  ((32 * dc + 8 * g) ^ ((c & 7) << 4)));
      acc = mfma16(a, wA[dc], acc);
    }
    if (w < 4) {                     // D: row n = sb*16+4g+r, col kd = c
      #pragma unroll
      for (int r = 0; r < 4; ++r)
        sm.Kl[(base + sb * 16 + 4 * g + r) * KP + c] = (_Float16)acc[r];
    } else {
      #pragma unroll
      for (int r = 0; r < 4; ++r)
        sm.Vt[c * VP + base + sb * 16 + 4 * g + r] = (_Float16)acc[r];
    }
    __syncthreads();
  }

  // ---- per Q-chunk: project Q, then attention ----
  for (int qc = 0; qc < NQC; ++qc) {
    const int qbase = qc * QCH;
    const int qcnt  = (Lq - qbase < QCH) ? (Lq - qbase) : QCH;
    const int nst   = (qcnt + 63) / 64;
    for (int st = 0; st < nst; ++st) {
      #pragma unroll
      for (int i = 0; i < 4; ++i) {  // stage 64 q rows
        int idx = tid + i * 512, r = idx >> 5, jj = idx & 31;
        int qs = qbase + st * 64 + r;
        int gq = QOFF + (qs < Lq ? qs : Lq - 1);
        float4 v = ((const float4*)(q + ((size_t)b * G + gq) * D))[jj];
        v4h hv = {(_Float16)v.x, (_Float16)v.y, (_Float16)v.z, (_Float16)v.w};
        *(v4h*)(sm.ht + r * 256 + ((8 * jj) ^ ((r & 7) << 4))) = hv;
      }
      __syncthreads();
      if (w < 4) {
        v4f acc = {0.f, 0.f, 0.f, 0.f};
        #pragma unroll
        for (int dc = 0; dc < 8; ++dc) {
          const v4h a = *(const v4h*)(sm.ht + (w * 16 + c) * 256 +
                                      ((32 * dc + 8 * g) ^ ((c & 7) << 4)));
          acc = mfma16(a, wQ[dc], acc);
        }
        #pragma unroll
        for (int r = 0; r < 4; ++r)
          sm.Ql[(st * 64 + w * 16 + 4 * g + r) * QP + c] = (_Float16)acc[r];
      }
      __syncthreads();
    }

    // attention: each wave owns up to 2 query-tiles of 16
    const int ntiles = (qcnt + 15) / 16;
    for (int jt = 0; jt < 2; ++jt) {
      const int tt = 2 * w + jt;
      if (tt >= ntiles) continue;
      const v4h qf = *(const v4h*)(sm.Ql + (tt * 16 + c) * QP + 4 * g);
      float m = -3.0e38f, lsum = 0.f;   // lsum: per-lane partial (own n-slots)
      v4f o = {0.f, 0.f, 0.f, 0.f};     // O^T tile: row kd=4g+r, col q=c
      for (int ch = 0; ch < NCH2; ++ch) {
        const int nb = ch * 32;
        const v4h k0 = *(const v4h*)(sm.Kl + (nb + c) * KP + 4 * g);
        const v4h k1 = *(const v4h*)(sm.Kl + (nb + 16 + c) * KP + 4 * g);
        const v4f z = {0.f, 0.f, 0.f, 0.f};
        v4f s0 = mfma16(k0, qf, z);     // S^T[n][q]: n=nb+4g+r, q=c
        v4f s1 = mfma16(k1, qf, z);     // n=nb+16+4g+r
        if constexpr ((Ln & 31) != 0) { // mask tail keys
          if (ch == NCH2 - 1) {
            #pragma unroll
            for (int r = 0; r < 4; ++r) {
              if (nb + 4 * g + r >= Ln)      s0[r] = -3.0e38f;
              if (nb + 16 + 4 * g + r >= Ln) s1[r] = -3.0e38f;
            }
          }
        }
        float mx = fmaxf(fmaxf(fmaxf(s0[0], s0[1]), fmaxf(s0[2], s0[3])),
                         fmaxf(fmaxf(s1[0], s1[1]), fmaxf(s1[2], s1[3])));
        mx = fmaxf(mx, __shfl_xor(mx, 16));   // reduce over g: m replicated per q=c
        mx = fmaxf(mx, __shfl_xor(mx, 32));
        const float nm = fmaxf(m, mx);
        const float sc = __expf(m - nm);
        lsum *= sc;
        o *= sc;
        m = nm;
        v4h p0, p1;
        #pragma unroll
        for (int r = 0; r < 4; ++r) { float e = __expf(s0[r] - m); lsum += e; p0[r] = (_Float16)e; }
        #pragma unroll
        for (int r = 0; r < 4; ++r) { float e = __expf(s1[r] - m); lsum += e; p1[r] = (_Float16)e; }
        const v4h v0 = *(const v4h*)(sm.Vt + c * VP + nb + 4 * g);
        const v4h v1 = *(const v4h*)(sm.Vt + c * VP + nb + 16 + 4 * g);
        o = mfma16(v0, p0, o);          // O^T += V^T * P^T  (P^T regs feed B directly)
        o = mfma16(v1, p1, o);
      }
      lsum += __shfl_xor(lsum, 16);
      lsum += __shfl_xor(lsum, 32);
      const float inv = 1.0f / lsum;
      // transpose O^T -> [q][kd] via per-wave LDS scratch, then coalesced store
      float* scr = (float*)(sm.ht + w * 1280);  // 16 x 20 f32
      #pragma unroll
      for (int r = 0; r < 4; ++r) scr[c * 20 + 4 * g + r] = o[r] * inv;
      const int row = lane >> 2, c4 = lane & 3; // wave-synchronous LDS reuse
      float4 val = *(const float4*)(scr + row * 20 + 4 * c4);
      const int qloc = qbase + tt * 16 + row;
      if (qloc < Lq)
        *(float4*)(heads + ((size_t)b * G + QOFF + qloc) * 128 + hh * 16 + 4 * c4) = val;
    }
    __syncthreads();
  }
}

// In-place output projection: row (b,g) of `data` holds heads [h*16+k] (128);
// out[b,g,e] = sum_hk heads[hk] * Wout[hk][e].
__global__ __launch_bounds__(256)
void out_proj_kernel(float* __restrict__ data, const float* __restrict__ Wout)
{
  __shared__ float Alds[64 * 128]; // 32 KB
  const int tid = threadIdx.x;
  const size_t rowbase = (size_t)blockIdx.x * 64;
  #pragma unroll
  for (int i = 0; i < 8; ++i) {
    int idx = tid + i * 256;
    ((float4*)Alds)[idx] = ((const float4*)(data + rowbase * 128))[idx];
  }
  __syncthreads();
  const int eq = tid & 31;
  const int r0 = tid >> 5;
  float4 accv[8];
  #pragma unroll
  for (int i = 0; i < 8; ++i) accv[i] = make_float4(0.f, 0.f, 0.f, 0.f);
  for (int d = 0; d < 128; ++d) {
    float4 w = ((const float4*)(Wout + (size_t)d * 128))[eq];
    #pragma unroll
    for (int i = 0; i < 8; ++i) {
      float a = Alds[(r0 + i * 8) * 128 + d];
      accv[i].x += a * w.x; accv[i].y += a * w.y;
      accv[i].z += a * w.z; accv[i].w += a * w.w;
    }
  }
  #pragma unroll
  for (int i = 0; i < 8; ++i)
    ((float4*)(data + (rowbase + r0 + i * 8) * 128))[eq] = accv[i];
}

} // namespace

extern "C" void kernel_launch(void* const* d_in, const int* in_sizes, int n_in,
                              void* d_out, int out_size, void* d_ws, size_t ws_size,
                              hipStream_t stream) {
  const float* q    = (const float*)d_in[0];
  const float* h    = (const float*)d_in[1];
  const float* Wqd  = (const float*)d_in[2];
  const float* Wkc  = (const float*)d_in[3];
  const float* Wvc  = (const float*)d_in[4];
  const float* Wqs  = (const float*)d_in[5];
  const float* Wko  = (const float*)d_in[6];
  const float* Wvo  = (const float*)d_in[7];
  const float* Wqc  = (const float*)d_in[8];
  const float* Wka  = (const float*)d_in[9];
  const float* Wva  = (const float*)d_in[10];
  const float* Wout = (const float*)d_in[11];
  float* out = (float*)d_out;  // heads buffer, then transformed in place

  attn_seg_kernel<0><<<B * H, 512, 0, stream>>>(q, h, Wqd, Wkc, Wvc, out);
  attn_seg_kernel<1><<<B * H, 512, 0, stream>>>(q, h, Wqs, Wko, Wvo, out);
  attn_seg_kernel<2><<<B * H, 512, 0, stream>>>(q, h, Wqc, Wka, Wva, out);
  out_proj_kernel<<<G * B / 64, 256, 0, stream>>>(out, Wout);
}

// Round 4
// 89.829 us; speedup vs baseline: 5.8145x; 1.1804x over previous
//
#include <hip/hip_runtime.h>
#include <hip/hip_bf16.h>

namespace {

typedef _Float16 v4h __attribute__((ext_vector_type(4)));
typedef __fp16   h2  __attribute__((ext_vector_type(2)));  // cvt_pkrtz return type
typedef float    v4f __attribute__((ext_vector_type(4)));

constexpr int B = 64, G = 512, D = 128, H = 8, KD = 16, NS = 20;
constexpr float NORM = 0.25f;        // 1/sqrt(KD)
constexpr float L2E  = 1.44269504088896f; // folded into Wq with NORM
constexpr float DTHR = 11.54f;       // defer-max threshold (8 nats, log2 dom.)
constexpr int KP = 20;               // Kl row pad (f16), 40 B rows
constexpr int VP = 524;              // Vt row pad (f16), 1048 B rows
constexpr int QP = 20;               // Ql row pad
constexpr int QCH = 256;             // queries per LDS-resident chunk

__device__ __forceinline__ v4f mfma16(v4h a, v4h b, v4f c) {
  // D = A(16xK16)*B(K16x16)+C. A: lane holds A[l&15][4*(l>>4)+i];
  // B: lane holds B[4*(l>>4)+i][l&15]; D: row=4*(l>>4)+i, col=l&15.
  return __builtin_amdgcn_mfma_f32_16x16x16f16(a, b, c, 0, 0, 0);
}
__device__ __forceinline__ v4h cvt4(float4 v) {
  h2 a = __builtin_amdgcn_cvt_pkrtz(v.x, v.y);
  h2 b = __builtin_amdgcn_cvt_pkrtz(v.z, v.w);
  return v4h{(_Float16)a[0], (_Float16)a[1], (_Float16)b[0], (_Float16)b[1]};
}

// One block (512 thr = 8 waves) per (b, head). blockIdx = hh*64 + b so the 8
// head-blocks of one batch share an XCD (round-robin %8 = b%8) -> h[b] L2-hot.
template<int SEG>
__global__ __launch_bounds__(512, 4)
void attn_seg_kernel(const float* __restrict__ q, const float* __restrict__ hb,
                     const float* __restrict__ Wq, const float* __restrict__ Wk,
                     const float* __restrict__ Wv, float* __restrict__ heads)
{
  constexpr int Lq   = SEG == 0 ? 1 : SEG == 1 ? NS : G - 1 - NS;  // 1,20,491
  constexpr int QOFF = SEG == 0 ? 0 : SEG == 1 ? 1  : 1 + NS;
  constexpr int Ln   = SEG == 0 ? G - 1 - NS : SEG == 1 ? G - NS : G; // 491,492,512
  constexpr int NCH2 = (Ln + 31) / 32;   // 32-key chunks
  constexpr int NST  = (Ln + 63) / 64;   // 64-row staging chunks
  constexpr int NQC  = (Lq + QCH - 1) / QCH;

  __shared__ alignas(16) struct {
    char      ht[16384];            // 64 x 128 f16, 256 B rows, XOR-swizzled
    _Float16  Kl[512 * KP];         // K  [n][kd]
    _Float16  Vt[16 * VP];          // V^T[kd][n]
    _Float16  Ql[QCH * QP];         // Q  [q][kd] (norm*log2e folded)
  } sm;                             // 63,872 B

  const int hh   = blockIdx.x >> 6;
  const int b    = blockIdx.x & 63;
  const int tid  = threadIdx.x;
  const int w    = tid >> 6;
  const int lane = tid & 63;
  const int g    = lane >> 4, c = lane & 15;

  // ---- W fragments in registers (B-operand layout) ----
  v4h wA[8];                        // waves 0-3: Wk, waves 4-7: Wv
  v4h wQ[8];                        // waves 0-3 only
  {
    const float* Wt = (w < 4) ? Wk : Wv;
    #pragma unroll
    for (int dc = 0; dc < 8; ++dc)
      #pragma unroll
      for (int bb = 0; bb < 4; ++bb)
        wA[dc][bb] = (_Float16)Wt[((size_t)hh * D + dc * 16 + 4 * g + bb) * KD + c];
    if (w < 4) {
      #pragma unroll
      for (int dc = 0; dc < 8; ++dc)
        #pragma unroll
        for (int bb = 0; bb < 4; ++bb)
          wQ[dc][bb] = (_Float16)(Wq[((size_t)hh * D + dc * 16 + 4 * g + bb) * KD + c]
                                  * (NORM * L2E));
    }
  }

  // ---- Phase B: K/V projection (K/V LDS-resident for whole block) ----
  const int sb = w & 3;
  for (int t = 0; t < NST; ++t) {
    const int base = t * 64;
    #pragma unroll
    for (int i = 0; i < 4; ++i) {    // stage 64 h rows -> f16 swizzled
      int idx = tid + i * 512, r = idx >> 5, jj = idx & 31;
      int n = base + r;
      int nn = n < Ln ? n : Ln - 1;
      int hr;
      if (SEG == 0)      hr = nn + 1 + NS;
      else if (SEG == 1) hr = (nn == 0) ? 0 : nn + NS;
      else               hr = nn;
      float4 v = ((const float4*)(hb + ((size_t)b * G + hr) * D))[jj];
      *(v4h*)(sm.ht + r * 256 + ((8 * jj) ^ ((r & 7) << 4))) = cvt4(v);
    }
    __syncthreads();
    v4f acc = {0.f, 0.f, 0.f, 0.f};
    #pragma unroll
    for (int dc = 0; dc < 8; ++dc) {
      const v4h a = *(const v4h*)(sm.ht + (sb * 16 + c) * 256 +
                                  ((32 * dc + 8 * g) ^ ((c & 7) << 4)));
      acc = mfma16(a, wA[dc], acc);
    }
    if (w < 4) {                     // D: row n = sb*16+4g+r, col kd = c
      #pragma unroll
      for (int r = 0; r < 4; ++r)
        sm.Kl[(base + sb * 16 + 4 * g + r) * KP + c] = (_Float16)acc[r];
    } else {
      #pragma unroll
      for (int r = 0; r < 4; ++r)
        sm.Vt[c * VP + base + sb * 16 + 4 * g + r] = (_Float16)acc[r];
    }
    __syncthreads();
  }

  // ---- per Q-chunk: project Q, then attention ----
  for (int qc = 0; qc < NQC; ++qc) {
    const int qbase = qc * QCH;
    const int qcnt  = (Lq - qbase < QCH) ? (Lq - qbase) : QCH;
    const int nst   = (qcnt + 63) / 64;
    for (int st = 0; st < nst; ++st) {
      #pragma unroll
      for (int i = 0; i < 4; ++i) {  // stage 64 q rows
        int idx = tid + i * 512, r = idx >> 5, jj = idx & 31;
        int qs = qbase + st * 64 + r;
        int gq = QOFF + (qs < Lq ? qs : Lq - 1);
        float4 v = ((const float4*)(q + ((size_t)b * G + gq) * D))[jj];
        *(v4h*)(sm.ht + r * 256 + ((8 * jj) ^ ((r & 7) << 4))) = cvt4(v);
      }
      __syncthreads();
      if (w < 4) {
        v4f acc = {0.f, 0.f, 0.f, 0.f};
        #pragma unroll
        for (int dc = 0; dc < 8; ++dc) {
          const v4h a = *(const v4h*)(sm.ht + (w * 16 + c) * 256 +
                                      ((32 * dc + 8 * g) ^ ((c & 7) << 4)));
          acc = mfma16(a, wQ[dc], acc);
        }
        #pragma unroll
        for (int r = 0; r < 4; ++r)
          sm.Ql[(st * 64 + w * 16 + 4 * g + r) * QP + c] = (_Float16)acc[r];
      }
      __syncthreads();
    }

    // ---- attention: tiles of 16 queries, strided over waves ----
    const int ntiles = (qcnt + 15) / 16;
    for (int tt = w; tt < ntiles; tt += 8) {
      const v4h qf = *(const v4h*)(sm.Ql + (tt * 16 + c) * QP + 4 * g);
      const _Float16* Kb = sm.Kl + c * KP + 4 * g;       // + ch*32*KP
      const _Float16* Vb = sm.Vt + c * VP + 4 * g;       // + ch*32
      float m = -1e30f;               // log2-domain running max (per query)
      v4f o    = {0.f, 0.f, 0.f, 0.f}; // O^T: row kd=4g+r, col q=c
      v4f lacc = {0.f, 0.f, 0.f, 0.f}; // ones-MFMA row-sums (replicated)
      const v4h ones = {(_Float16)1.f, (_Float16)1.f, (_Float16)1.f, (_Float16)1.f};
      const v4f z = {0.f, 0.f, 0.f, 0.f};
      #pragma unroll
      for (int ch = 0; ch < NCH2; ++ch) {
        const int nb = ch * 32;
        const v4h k0 = *(const v4h*)(Kb + nb * KP);
        const v4h k1 = *(const v4h*)(Kb + (nb + 16) * KP);
        v4f s0 = mfma16(k0, qf, z);   // S^T[n][q] (log2 dom.): n=nb+4g+r, q=c
        v4f s1 = mfma16(k1, qf, z);   // n=nb+16+4g+r
        if constexpr ((Ln & 31) != 0) {
          if (ch == NCH2 - 1) {
            #pragma unroll
            for (int r = 0; r < 4; ++r) {
              if (nb + 4 * g + r >= Ln)      s0[r] = -1e30f;
              if (nb + 16 + 4 * g + r >= Ln) s1[r] = -1e30f;
            }
          }
        }
        float mx = fmaxf(fmaxf(fmaxf(s0[0], s0[1]), s0[2]),
                         fmaxf(fmaxf(s0[3], s1[0]), fmaxf(fmaxf(s1[1], s1[2]), s1[3])));
        if (!__all(mx <= m + DTHR)) { // rare: max grew beyond defer threshold
          mx = fmaxf(mx, __shfl_xor(mx, 16));
          mx = fmaxf(mx, __shfl_xor(mx, 32));
          const float nm = fmaxf(m, mx);
          const float sc = __builtin_amdgcn_exp2f(m - nm);
          o *= sc; lacc *= sc;
          m = nm;
        }
        h2 e01 = __builtin_amdgcn_cvt_pkrtz(__builtin_amdgcn_exp2f(s0[0] - m),
                                            __builtin_amdgcn_exp2f(s0[1] - m));
        h2 e23 = __builtin_amdgcn_cvt_pkrtz(__builtin_amdgcn_exp2f(s0[2] - m),
                                            __builtin_amdgcn_exp2f(s0[3] - m));
        h2 e45 = __builtin_amdgcn_cvt_pkrtz(__builtin_amdgcn_exp2f(s1[0] - m),
                                            __builtin_amdgcn_exp2f(s1[1] - m));
        h2 e67 = __builtin_amdgcn_cvt_pkrtz(__builtin_amdgcn_exp2f(s1[2] - m),
                                            __builtin_amdgcn_exp2f(s1[3] - m));
        const v4h p0 = {(_Float16)e01[0], (_Float16)e01[1], (_Float16)e23[0], (_Float16)e23[1]};
        const v4h p1 = {(_Float16)e45[0], (_Float16)e45[1], (_Float16)e67[0], (_Float16)e67[1]};
        const v4h v0 = *(const v4h*)(Vb + nb);
        const v4h v1 = *(const v4h*)(Vb + nb + 16);
        o = mfma16(v0, p0, o);        // O^T += V^T * P^T
        o = mfma16(v1, p1, o);
        lacc = mfma16(ones, p0, lacc);
        lacc = mfma16(ones, p1, lacc);
      }
      const float inv = 1.0f / lacc[0]; // colsum replicated across rows
      // transpose O^T -> [q][kd] via per-wave LDS scratch, coalesced store
      float* scr = (float*)(sm.ht + w * 1280);  // 16 x 20 f32
      #pragma unroll
      for (int r = 0; r < 4; ++r) scr[c * 20 + 4 * g + r] = o[r] * inv;
      const int row = lane >> 2, c4 = lane & 3; // wave-synchronous LDS reuse
      float4 val = *(const float4*)(scr + row * 20 + 4 * c4);
      const int qloc = qbase + tt * 16 + row;
      if (qloc < Lq)
        *(float4*)(heads + ((size_t)b * G + QOFF + qloc) * 128 + hh * 16 + 4 * c4) = val;
    }
    __syncthreads();
  }
}

// In-place output projection: row (b,g) of `data` holds heads [h*16+k] (128);
// out[b,g,e] = sum_hk heads[hk] * Wout[hk][e].
__global__ __launch_bounds__(256)
void out_proj_kernel(float* __restrict__ data, const float* __restrict__ Wout)
{
  __shared__ float Alds[64 * 128]; // 32 KB
  const int tid = threadIdx.x;
  const size_t rowbase = (size_t)blockIdx.x * 64;
  #pragma unroll
  for (int i = 0; i < 8; ++i) {
    int idx = tid + i * 256;
    ((float4*)Alds)[idx] = ((const float4*)(data + rowbase * 128))[idx];
  }
  __syncthreads();
  const int eq = tid & 31;
  const int r0 = tid >> 5;
  float4 accv[8];
  #pragma unroll
  for (int i = 0; i < 8; ++i) accv[i] = make_float4(0.f, 0.f, 0.f, 0.f);
  for (int d = 0; d < 128; ++d) {
    float4 w = ((const float4*)(Wout + (size_t)d * 128))[eq];
    #pragma unroll
    for (int i = 0; i < 8; ++i) {
      float a = Alds[(r0 + i * 8) * 128 + d];
      accv[i].x += a * w.x; accv[i].y += a * w.y;
      accv[i].z += a * w.z; accv[i].w += a * w.w;
    }
  }
  #pragma unroll
  for (int i = 0; i < 8; ++i)
    ((float4*)(data + (rowbase + r0 + i * 8) * 128))[eq] = accv[i];
}

} // namespace

extern "C" void kernel_launch(void* const* d_in, const int* in_sizes, int n_in,
                              void* d_out, int out_size, void* d_ws, size_t ws_size,
                              hipStream_t stream) {
  const float* q    = (const float*)d_in[0];
  const float* h    = (const float*)d_in[1];
  const float* Wqd  = (const float*)d_in[2];
  const float* Wkc  = (const float*)d_in[3];
  const float* Wvc  = (const float*)d_in[4];
  const float* Wqs  = (const float*)d_in[5];
  const float* Wko  = (const float*)d_in[6];
  const float* Wvo  = (const float*)d_in[7];
  const float* Wqc  = (const float*)d_in[8];
  const float* Wka  = (const float*)d_in[9];
  const float* Wva  = (const float*)d_in[10];
  const float* Wout = (const float*)d_in[11];
  float* out = (float*)d_out;  // heads buffer, then transformed in place

  attn_seg_kernel<0><<<B * H, 512, 0, stream>>>(q, h, Wqd, Wkc, Wvc, out);
  attn_seg_kernel<1><<<B * H, 512, 0, stream>>>(q, h, Wqs, Wko, Wvo, out);
  attn_seg_kernel<2><<<B * H, 512, 0, stream>>>(q, h, Wqc, Wka, Wva, out);
  out_proj_kernel<<<G * B / 64, 256, 0, stream>>>(out, Wout);
}